// Round 4
// baseline (238.369 us; speedup 1.0000x reference)
//
#include <hip/hip_runtime.h>
#include <math.h>

// B=8, N=128, H2=800, FD=500, P=100
#define FD 500
#define H2 800
#define NRR 1024          // rows = 8*128
#define NPAD 2048         // padded feature cols (2000 real)
#define NKS 25            // 800 / 32

#define NEG_HUGE (-1.0e30f)  // stands in for -inf (ref has -inf -> threshold inf)

typedef __bf16 bf16x8 __attribute__((ext_vector_type(8)));
typedef float f32x4 __attribute__((ext_vector_type(4)));

union ChunkU { uint4 u; bf16x8 b; __bf16 h[8]; };

__device__ __forceinline__ float fast_tanh(float x) {
    float e = __expf(2.0f * x);
    return 1.0f - 2.0f / (e + 1.0f);
}

__device__ __forceinline__ bf16x8 as_frag(uint4 v) { ChunkU c; c.u = v; return c.b; }

// ---------------------------------------------------------------------------
// Kernel 1: convert f32 -> bf16 hi/lo fragment-linear tiles (blocks 0..239),
//           + prep (selectors S8, bias_c, consts) in block 240.
//  Tile (rb/cb, ks) = 512 uint4 chunks; chunk (h,f,l) holds
//  M[row = f*16 + (l&15)][k = ks*32 + (l>>4)*8 .. +7] (h=0 hi, h=1 lo).
//  Each convert block: one 64-row tile x 160-k slab, coalesced loads via LDS.
// ---------------------------------------------------------------------------
#define CV_STRIDE 164   // LDS row stride (floats): %32==4 -> 2-way (free) on readback

__global__ __launch_bounds__(256) void convert_prep_kernel(
        const float* __restrict__ hidden,
        const float* __restrict__ Wh, const float* __restrict__ Wm,
        const float* __restrict__ Ws, const float* __restrict__ Wg,
        uint4* __restrict__ A_t, uint4* __restrict__ B_t,
        const float* __restrict__ W_gp, const float* __restrict__ b_gp,
        const float* __restrict__ W_sp, const float* __restrict__ b_sp,
        const float* __restrict__ W_rp, const float* __restrict__ b_rp,
        const float* __restrict__ w_go, const float* __restrict__ b_go,
        const float* __restrict__ w_so, const float* __restrict__ b_so,
        const float* __restrict__ bh, const float* __restrict__ bm,
        const float* __restrict__ bs, const float* __restrict__ bg,
        float* __restrict__ S8, float* __restrict__ bias_c,
        float* __restrict__ consts) {
    __shared__ float Ls[64 * CV_STRIDE];   // 42 KB
    int blk = blockIdx.x;
    int t = threadIdx.x;

    if (blk == 240) {
        // ---- prep path: selectors (8x512 in LDS), S8[8][2048], bias_c, consts
        float* selL = Ls;   // 8*512 floats
        for (int v = 0; v < 8; ++v) {
            const float* wvec; const float* mat; int cols; int off;
            if (v < 3)      { wvec = w_go; mat = W_gp; cols = 3*FD; off = v*FD; }
            else if (v < 6) { wvec = w_so; mat = W_sp; cols = 3*FD; off = (v-3)*FD; }
            else            { wvec = w_go; mat = W_rp; cols = 2*FD; off = (v-6)*FD; }
            for (int f = t; f < 512; f += 256) {
                float s = 0.f;
                if (f < FD) {
                    #pragma unroll 4
                    for (int p = 0; p < 100; ++p) s += wvec[p] * mat[p*cols + off + f];
                }
                selL[v*512 + f] = s;
            }
        }
        if (t < 3) {
            const float* bv = (t==0) ? b_gp : (t==1) ? b_sp : b_rp;
            const float* wv = (t==1) ? w_so : w_go;
            float s = (t==1) ? b_so[0] : b_go[0];
            for (int p = 0; p < 100; ++p) s += bv[p] * wv[p];
            consts[t] = s;
        }
        __syncthreads();
        for (int c = t; c < NPAD; c += 256) {
            float v[8] = {0,0,0,0,0,0,0,0};
            float bias = 0.f;
            if (c < 2000) {
                int tt = c / FD, f = c % FD;
                if (tt == 0)      { v[1]=selL[1*512+f]; v[5]=selL[3*512+f]; v[7]=selL[6*512+f]; bias=bh[f]; }
                else if (tt == 1) { v[0]=selL[2*512+f]; v[3]=selL[5*512+f]; v[6]=selL[7*512+f]; bias=bm[f]; }
                else if (tt == 2) { v[4]=selL[4*512+f]; bias=bs[f]; }
                else              { v[2]=selL[0*512+f]; bias=bg[f]; }
            }
            #pragma unroll
            for (int q = 0; q < 8; ++q) S8[q*NPAD + c] = v[q];
            bias_c[c] = bias;
        }
        return;
    }

    // ---- convert path ----
    bool isA = blk < 80;                      // A: 16 rb * 5 slabs; B: 32 cb * 5
    int tile = isA ? (blk / 5) : ((blk - 80) / 5);
    int slab = isA ? (blk % 5) : ((blk - 80) % 5);   // k in [slab*160, +160)

    // load phase: 64 rows x 160 k, coalesced float4
    #pragma unroll
    for (int i = 0; i < 10; ++i) {
        int idx = t + i*256;                  // 0..2559
        int row = idx / 40;                   // 40 float4 per row
        int kq  = idx - row*40;
        float4 v = {0.f,0.f,0.f,0.f};
        if (isA) {
            int grow = tile*64 + row;
            v = *(const float4*)(hidden + (size_t)grow*H2 + slab*160 + kq*4);
        } else {
            int c = tile*64 + row;
            if (c < 2000) {
                int wt = c / FD, wf = c % FD;
                const float* wm = (wt==0)?Wh:(wt==1)?Wm:(wt==2)?Ws:Wg;
                v = *(const float4*)(wm + (size_t)wf*H2 + slab*160 + kq*4);
            }
        }
        *(float4*)&Ls[row*CV_STRIDE + kq*4] = v;
    }
    __syncthreads();

    // write phase: fragment-linear chunks, coalesced global stores
    int f = t >> 6, l = t & 63;
    int lrow  = f*16 + (l & 15);
    int koff0 = (l >> 4) * 8;
    uint4* dstbase = (isA ? A_t : B_t) + (size_t)tile * NKS * 512;
    #pragma unroll
    for (int ksl = 0; ksl < 5; ++ksl) {
        int ks = slab*5 + ksl;
        const float* src = &Ls[lrow*CV_STRIDE + ksl*32 + koff0];
        ChunkU hc, lo;
        #pragma unroll
        for (int j = 0; j < 8; ++j) {
            float x = src[j];
            __bf16 h = (__bf16)x;
            hc.h[j] = h;
            lo.h[j] = (__bf16)(x - (float)h);
        }
        uint4* dst = dstbase + (size_t)ks * 512;
        dst[(0*4 + f)*64 + l] = hc.u;
        dst[(1*4 + f)*64 + l] = lo.u;
    }
}

// ---------------------------------------------------------------------------
// Kernel 2: MFMA GEMM (bf16 2-term split, 3 products) + fused tanh + selector
//  reduction. Block tile 64x64, 4 waves, KS=32, double-buffered LDS.
//  XCD-aware swizzle: each XCD owns an 8x8 tile rectangle (3.2 MB < 4 MB L2).
// ---------------------------------------------------------------------------
__global__ __launch_bounds__(256, 2) void gemm_kernel(
        const uint4* __restrict__ A_t, const uint4* __restrict__ B_t,
        const float* __restrict__ S8, const float* __restrict__ bias_c,
        float* __restrict__ partials) {
    __shared__ uint4 Abuf[2][512];
    __shared__ uint4 Bbuf[2][512];
    int tid = threadIdx.x;

    // swizzle blocks so each XCD (assumed lin%8) gets an 8rb x 8cb rectangle
    int lin = blockIdx.y * 32 + blockIdx.x;   // 0..511
    int xcd = lin & 7;
    int w   = lin >> 3;                       // 0..63
    int rb  = (xcd & 1)*8 + (w & 7);          // 0..15
    int cb  = (xcd >> 1)*8 + (w >> 3);        // 0..31

    int l  = tid & 63;
    int wid = tid >> 6;
    int wr = wid >> 1, wc = wid & 1;

    const uint4* Ablk = A_t + (size_t)rb * NKS * 512;
    const uint4* Bblk = B_t + (size_t)cb * NKS * 512;

    uint4 st[4];
    #define STAGE_LOAD(ks) do { \
        const uint4* s_ = (tid < 128) ? (Ablk + (ks)*512 + tid) : (Bblk + (ks)*512 + (tid-128)); \
        st[0]=s_[0]; st[1]=s_[128]; st[2]=s_[256]; st[3]=s_[384]; } while(0)
    #define STAGE_WRITE(buf) do { \
        uint4* d_ = (tid < 128) ? &Abuf[buf][tid] : &Bbuf[buf][tid-128]; \
        d_[0]=st[0]; d_[128]=st[1]; d_[256]=st[2]; d_[384]=st[3]; } while(0)

    f32x4 acc[2][2];
    #pragma unroll
    for (int m=0;m<2;++m)
        #pragma unroll
        for (int n=0;n<2;++n) acc[m][n] = (f32x4){0.f,0.f,0.f,0.f};

    STAGE_LOAD(0); STAGE_WRITE(0);
    __syncthreads();
    STAGE_LOAD(1);

    for (int ks = 0; ks < NKS; ++ks) {
        int cur = ks & 1;
        int fa = wr*2, fb = wc*2;
        bf16x8 a_h[2], a_l[2], b_h[2], b_l[2];
        #pragma unroll
        for (int m=0;m<2;++m) {
            a_h[m] = as_frag(Abuf[cur][(0 + fa + m)*64 + l]);
            a_l[m] = as_frag(Abuf[cur][(4 + fa + m)*64 + l]);
        }
        #pragma unroll
        for (int n=0;n<2;++n) {
            b_h[n] = as_frag(Bbuf[cur][(0 + fb + n)*64 + l]);
            b_l[n] = as_frag(Bbuf[cur][(4 + fb + n)*64 + l]);
        }
        #pragma unroll
        for (int m=0;m<2;++m)
            #pragma unroll
            for (int n=0;n<2;++n) {
                acc[m][n] = __builtin_amdgcn_mfma_f32_16x16x32_bf16(a_h[m], b_h[n], acc[m][n], 0,0,0);
                acc[m][n] = __builtin_amdgcn_mfma_f32_16x16x32_bf16(a_h[m], b_l[n], acc[m][n], 0,0,0);
                acc[m][n] = __builtin_amdgcn_mfma_f32_16x16x32_bf16(a_l[m], b_h[n], acc[m][n], 0,0,0);
            }
        if (ks + 1 < NKS) {
            __syncthreads();
            STAGE_WRITE((ks+1) & 1);
            __syncthreads();
            if (ks + 2 < NKS) STAGE_LOAD(ks+2);
        }
    }

    // ---- epilogue: tanh+bias into LDS Y[64][64], then float4 selector reduce
    int lr = l >> 4, lc = l & 15;
    __syncthreads();
    float* Y = (float*)Abuf;               // 16 KB
    #pragma unroll
    for (int n=0;n<2;++n) {
        int col_local = (wc*2 + n)*16 + lc;
        float bias = bias_c[cb*64 + col_local];
        #pragma unroll
        for (int m=0;m<2;++m) {
            int row_base = (wr*2 + m)*16 + lr*4;
            #pragma unroll
            for (int r=0;r<4;++r)
                Y[(row_base + r)*64 + col_local] = fast_tanh(acc[m][n][r] + bias);
        }
    }
    __syncthreads();
    #pragma unroll
    for (int it=0; it<2; ++it) {
        int task = tid + it*256;
        int q = task & 7, row = task >> 3;
        const float4* s8r = (const float4*)(S8 + q*NPAD + cb*64);
        const float4* yr  = (const float4*)(Y + row*64);
        float s = 0.f;
        #pragma unroll
        for (int c4=0;c4<16;++c4) {
            float4 a = yr[c4], b = s8r[c4];
            s += a.x*b.x + a.y*b.y + a.z*b.z + a.w*b.w;
        }
        partials[((size_t)cb*NRR + rb*64 + row)*8 + q] = s;
    }
    #undef STAGE_LOAD
    #undef STAGE_WRITE
}

// ---------------------------------------------------------------------------
// Kernel 3: rowvals[r][q] = sum over 32 col-blocks of partials
// ---------------------------------------------------------------------------
__global__ void finish_kernel(const float* __restrict__ partials,
                              float* __restrict__ rowvals) {
    int t = blockIdx.x*256 + threadIdx.x;   // 0..8191 = row*8 + q
    float s = 0.f;
    #pragma unroll 8
    for (int cbk = 0; cbk < 32; ++cbk) s += partials[(size_t)cbk*8192 + t];
    rowvals[t] = s;
}

// ---------------------------------------------------------------------------
// Kernel 4: fill both (B,N,N,N) outputs via exp factorization:
//  tanh(u) = 1 - 2/(e^{2u}+1);  e^{2(gi+gk+c+gj)} = Eik * Egj[j]
// ---------------------------------------------------------------------------
#define KSPLIT 2
__global__ __launch_bounds__(256) void fill_kernel(
        const float* __restrict__ rowvals, const float* __restrict__ consts,
        float* __restrict__ grand, float* __restrict__ sib) {
    int bi = blockIdx.x;          // b*128 + i
    int kz = blockIdx.y;
    int b = bi >> 7;
    int i = bi & 127;
    int tid = threadIdx.x;

    __shared__ float gks[128], sks[128], Egj[128], Esj[128];
    if (tid < 128) {
        const float* rv = rowvals + (size_t)(b*128 + tid)*8;
        gks[tid] = rv[2];
        sks[tid] = rv[5];
        Egj[tid] = __expf(2.f * rv[1]);
        Esj[tid] = __expf(2.f * rv[4]);
    }
    __syncthreads();

    const float* rvi = rowvals + (size_t)bi * 8;
    float c_g = consts[0], c_s = consts[1], c_r = consts[2];
    float gic = rvi[0] + c_g;
    float sic = rvi[3] + c_s;
    float r0 = rowvals[(size_t)(b*128)*8 + 7];
    float rootv = fast_tanh(r0 + rvi[6] + c_r);

    size_t base = (size_t)bi * (128*128);
    int j4 = (tid & 31) * 4;
    int klo = tid >> 5;                  // 0..7
    const int KROWS = 128 / KSPLIT;      // 64

    for (int it = 0; it < KROWS/8; ++it) {
        int k = kz*KROWS + it*8 + klo;
        float Eg = __expf(2.f * (gic + gks[k]));
        float Es = __expf(2.f * (sic + sks[k]));
        float4 go, so;
        #pragma unroll
        for (int jj = 0; jj < 4; ++jj) {
            int j = j4 + jj;
            bool valid = (i != 0) && (i != j) && (j != k);
            float tg = Eg * Egj[j];
            float ts = Es * Esj[j];
            float g = 1.f - 2.f * __builtin_amdgcn_rcpf(tg + 1.f);
            float s = 1.f - 2.f * __builtin_amdgcn_rcpf(ts + 1.f);
            g = valid ? g : NEG_HUGE;
            s = valid ? s : 0.0f;
            if (i != 0 && k == 0 && j == 0) g = rootv;
            (&go.x)[jj] = g;
            (&so.x)[jj] = s;
        }
        size_t off = base + (size_t)k*128 + j4;
        *(float4*)(grand + off) = go;
        *(float4*)(sib + off) = so;
    }
}

// ---------------------------------------------------------------------------
extern "C" void kernel_launch(void* const* d_in, const int* in_sizes, int n_in,
                              void* d_out, int out_size, void* d_ws, size_t ws_size,
                              hipStream_t stream) {
    const float* hidden = (const float*)d_in[0];
    const float* Wh  = (const float*)d_in[1];   const float* bh  = (const float*)d_in[2];
    const float* Wm  = (const float*)d_in[3];   const float* bm  = (const float*)d_in[4];
    const float* Ws_ = (const float*)d_in[5];   const float* bs  = (const float*)d_in[6];
    const float* Wg  = (const float*)d_in[7];   const float* bg  = (const float*)d_in[8];
    const float* W_gp = (const float*)d_in[9];  const float* b_gp = (const float*)d_in[10];
    const float* W_sp = (const float*)d_in[11]; const float* b_sp = (const float*)d_in[12];
    const float* W_rp = (const float*)d_in[13]; const float* b_rp = (const float*)d_in[14];
    const float* w_go = (const float*)d_in[15]; const float* b_go = (const float*)d_in[16];
    const float* w_so = (const float*)d_in[17]; const float* b_so = (const float*)d_in[18];

    float* out   = (float*)d_out;
    float* grand = out;                        // 16777216 floats
    float* sib   = out + (size_t)16777216;     // 16777216 floats

    // bf16 tiled scratch in the grand half of d_out (consumed by gemm,
    // overwritten by fill which runs last in stream order).
    uint4* A_t = (uint4*)out;                  // 16*25*512 uint4 (3.28 MB)
    uint4* B_t = (uint4*)out + 204800;         // 32*25*512 uint4 (6.55 MB)

    // small scratch in d_ws (~1.2 MB)
    float* S8      = (float*)d_ws;             // 8*2048
    float* bias_c  = S8 + 16384;               // 2048
    float* consts  = bias_c + 2048;            // 16
    float* rowvals = consts + 16;              // 8192
    float* partials= rowvals + 8192;           // 32*1024*8 = 262144

    convert_prep_kernel<<<dim3(241), dim3(256), 0, stream>>>(
        hidden, Wh, Wm, Ws_, Wg, A_t, B_t,
        W_gp, b_gp, W_sp, b_sp, W_rp, b_rp, w_go, b_go, w_so, b_so,
        bh, bm, bs, bg, S8, bias_c, consts);
    gemm_kernel<<<dim3(32,16), dim3(256), 0, stream>>>(A_t, B_t, S8, bias_c, partials);
    finish_kernel<<<dim3(32), dim3(256), 0, stream>>>(partials, rowvals);
    fill_kernel<<<dim3(1024, KSPLIT), dim3(256), 0, stream>>>(rowvals, consts, grand, sib);
}

// Round 5
// 120.382 us; speedup vs baseline: 1.9801x; 1.9801x over previous
//
#include <hip/hip_runtime.h>
#include <math.h>

// B=8, N=128, H2=800, FD=500, P=100
#define FD 500
#define H2 800
#define NRR 1024          // rows = 8*128
#define NPAD 2048         // padded feature cols (2000 real)
#define NKS 25            // 800 / 32

#define NEG_HUGE (-1.0e30f)  // stands in for -inf (ref has -inf -> threshold inf)

typedef __bf16 bf16x8 __attribute__((ext_vector_type(8)));
typedef float f32x4 __attribute__((ext_vector_type(4)));

union ChunkU { uint4 u; bf16x8 b; __bf16 h[8]; };

__device__ __forceinline__ float fast_tanh(float x) {
    float e = __expf(2.0f * x);
    return 1.0f - 2.0f / (e + 1.0f);
}

__device__ __forceinline__ bf16x8 as_frag(uint4 v) { ChunkU c; c.u = v; return c.b; }

// ---------------------------------------------------------------------------
// Kernel 1a: selector vectors (8 x 500, stride 512) and 3 scalar constants.
//  8 blocks x 512 threads (proven fast in round 2; do NOT serialize into one
//  block — round 4's 223 us tail was exactly that).
// ---------------------------------------------------------------------------
__global__ void prep_kernel(const float* __restrict__ W_gp, const float* __restrict__ b_gp,
                            const float* __restrict__ W_sp, const float* __restrict__ b_sp,
                            const float* __restrict__ W_rp, const float* __restrict__ b_rp,
                            const float* __restrict__ w_go, const float* __restrict__ b_go,
                            const float* __restrict__ w_so, const float* __restrict__ b_so,
                            float* __restrict__ sel, float* __restrict__ consts) {
    int v = blockIdx.x;
    int f = threadIdx.x;
    const float* wvec; const float* mat; int cols; int off;
    if (v < 3)      { wvec = w_go; mat = W_gp; cols = 3*FD; off = v*FD; }
    else if (v < 6) { wvec = w_so; mat = W_sp; cols = 3*FD; off = (v-3)*FD; }
    else            { wvec = w_go; mat = W_rp; cols = 2*FD; off = (v-6)*FD; }
    if (f < FD) {
        float s = 0.f;
        #pragma unroll 4
        for (int p = 0; p < 100; ++p) s += wvec[p] * mat[p*cols + off + f];
        sel[v*512 + f] = s;
    }
    if (v == 0 && f >= FD && f < FD+3) {
        int which = f - FD;
        const float* bv; const float* wv; float badd;
        if (which == 0)      { bv = b_gp; wv = w_go; badd = b_go[0]; }
        else if (which == 1) { bv = b_sp; wv = w_so; badd = b_so[0]; }
        else                 { bv = b_rp; wv = w_go; badd = b_go[0]; }
        float s = badd;
        for (int p = 0; p < 100; ++p) s += bv[p] * wv[p];
        consts[which] = s;
    }
}

// ---------------------------------------------------------------------------
// Kernel 1b: build S8[8][2048] (selector-per-column) and bias_c[2048]
// ---------------------------------------------------------------------------
__global__ void prep2_kernel(const float* __restrict__ sel,
                             const float* __restrict__ bh, const float* __restrict__ bm,
                             const float* __restrict__ bs, const float* __restrict__ bg,
                             float* __restrict__ S8, float* __restrict__ bias_c) {
    int c = blockIdx.x * 256 + threadIdx.x;   // 0..2047
    float v[8] = {0,0,0,0,0,0,0,0};
    float bias = 0.f;
    if (c < 2000) {
        int t = c / FD, f = c % FD;
        if (t == 0)      { v[1]=sel[1*512+f]; v[5]=sel[3*512+f]; v[7]=sel[6*512+f]; bias=bh[f]; }
        else if (t == 1) { v[0]=sel[2*512+f]; v[3]=sel[5*512+f]; v[6]=sel[7*512+f]; bias=bm[f]; }
        else if (t == 2) { v[4]=sel[4*512+f]; bias=bs[f]; }
        else             { v[2]=sel[0*512+f]; bias=bg[f]; }
    }
    #pragma unroll
    for (int q = 0; q < 8; ++q) S8[q*NPAD + c] = v[q];
    bias_c[c] = bias;
}

// ---------------------------------------------------------------------------
// Kernel 2: convert f32 -> bf16 hi/lo fragment-linear tiles (240 blocks).
//  Tile (rb/cb, ks) = 512 uint4 chunks; chunk (h,f,l) holds
//  M[row = f*16 + (l&15)][k = ks*32 + (l>>4)*8 .. +7] (h=0 hi, h=1 lo).
//  Each block: one 64-row tile x 160-k slab, coalesced loads via LDS.
// ---------------------------------------------------------------------------
#define CV_STRIDE 164   // LDS row stride (floats)

__global__ __launch_bounds__(256) void convert_kernel(
        const float* __restrict__ hidden,
        const float* __restrict__ Wh, const float* __restrict__ Wm,
        const float* __restrict__ Ws, const float* __restrict__ Wg,
        uint4* __restrict__ A_t, uint4* __restrict__ B_t) {
    __shared__ float Ls[64 * CV_STRIDE];   // 42 KB
    int blk = blockIdx.x;
    int t = threadIdx.x;

    bool isA = blk < 80;                      // A: 16 rb * 5 slabs; B: 32 cb * 5
    int tile = isA ? (blk / 5) : ((blk - 80) / 5);
    int slab = isA ? (blk % 5) : ((blk - 80) % 5);   // k in [slab*160, +160)

    // load phase: 64 rows x 160 k, coalesced float4
    #pragma unroll
    for (int i = 0; i < 10; ++i) {
        int idx = t + i*256;                  // 0..2559
        int row = idx / 40;                   // 40 float4 per row
        int kq  = idx - row*40;
        float4 v = {0.f,0.f,0.f,0.f};
        if (isA) {
            int grow = tile*64 + row;
            v = *(const float4*)(hidden + (size_t)grow*H2 + slab*160 + kq*4);
        } else {
            int c = tile*64 + row;
            if (c < 2000) {
                int wt = c / FD, wf = c % FD;
                const float* wm = (wt==0)?Wh:(wt==1)?Wm:(wt==2)?Ws:Wg;
                v = *(const float4*)(wm + (size_t)wf*H2 + slab*160 + kq*4);
            }
        }
        *(float4*)&Ls[row*CV_STRIDE + kq*4] = v;
    }
    __syncthreads();

    // write phase: fragment-linear chunks, coalesced global stores
    int f = t >> 6, l = t & 63;
    int lrow  = f*16 + (l & 15);
    int koff0 = (l >> 4) * 8;
    uint4* dstbase = (isA ? A_t : B_t) + (size_t)tile * NKS * 512;
    #pragma unroll
    for (int ksl = 0; ksl < 5; ++ksl) {
        int ks = slab*5 + ksl;
        const float* src = &Ls[lrow*CV_STRIDE + ksl*32 + koff0];
        ChunkU hc, lo;
        #pragma unroll
        for (int j = 0; j < 8; ++j) {
            float x = src[j];
            __bf16 h = (__bf16)x;
            hc.h[j] = h;
            lo.h[j] = (__bf16)(x - (float)h);
        }
        uint4* dst = dstbase + (size_t)ks * 512;
        dst[(0*4 + f)*64 + l] = hc.u;
        dst[(1*4 + f)*64 + l] = lo.u;
    }
}

// ---------------------------------------------------------------------------
// Kernel 3: MFMA GEMM (bf16 2-term split, 3 products) + fused tanh + selector
//  reduction. Block tile 64x64, 4 waves, KS=32, double-buffered LDS.
//  XCD-aware swizzle: each XCD (lin%8) owns an 8x8 tile rectangle.
// ---------------------------------------------------------------------------
__global__ __launch_bounds__(256, 2) void gemm_kernel(
        const uint4* __restrict__ A_t, const uint4* __restrict__ B_t,
        const float* __restrict__ S8, const float* __restrict__ bias_c,
        float* __restrict__ partials) {
    __shared__ uint4 Abuf[2][512];
    __shared__ uint4 Bbuf[2][512];
    int tid = threadIdx.x;

    int lin = blockIdx.y * 32 + blockIdx.x;   // 0..511
    int xcd = lin & 7;
    int w   = lin >> 3;                       // 0..63
    int rb  = (xcd & 1)*8 + (w & 7);          // 0..15
    int cb  = (xcd >> 1)*8 + (w >> 3);        // 0..31

    int l  = tid & 63;
    int wid = tid >> 6;
    int wr = wid >> 1, wc = wid & 1;

    const uint4* Ablk = A_t + (size_t)rb * NKS * 512;
    const uint4* Bblk = B_t + (size_t)cb * NKS * 512;

    uint4 st[4];
    #define STAGE_LOAD(ks) do { \
        const uint4* s_ = (tid < 128) ? (Ablk + (ks)*512 + tid) : (Bblk + (ks)*512 + (tid-128)); \
        st[0]=s_[0]; st[1]=s_[128]; st[2]=s_[256]; st[3]=s_[384]; } while(0)
    #define STAGE_WRITE(buf) do { \
        uint4* d_ = (tid < 128) ? &Abuf[buf][tid] : &Bbuf[buf][tid-128]; \
        d_[0]=st[0]; d_[128]=st[1]; d_[256]=st[2]; d_[384]=st[3]; } while(0)

    f32x4 acc[2][2];
    #pragma unroll
    for (int m=0;m<2;++m)
        #pragma unroll
        for (int n=0;n<2;++n) acc[m][n] = (f32x4){0.f,0.f,0.f,0.f};

    STAGE_LOAD(0); STAGE_WRITE(0);
    __syncthreads();
    STAGE_LOAD(1);

    for (int ks = 0; ks < NKS; ++ks) {
        int cur = ks & 1;
        int fa = wr*2, fb = wc*2;
        bf16x8 a_h[2], a_l[2], b_h[2], b_l[2];
        #pragma unroll
        for (int m=0;m<2;++m) {
            a_h[m] = as_frag(Abuf[cur][(0 + fa + m)*64 + l]);
            a_l[m] = as_frag(Abuf[cur][(4 + fa + m)*64 + l]);
        }
        #pragma unroll
        for (int n=0;n<2;++n) {
            b_h[n] = as_frag(Bbuf[cur][(0 + fb + n)*64 + l]);
            b_l[n] = as_frag(Bbuf[cur][(4 + fb + n)*64 + l]);
        }
        #pragma unroll
        for (int m=0;m<2;++m)
            #pragma unroll
            for (int n=0;n<2;++n) {
                acc[m][n] = __builtin_amdgcn_mfma_f32_16x16x32_bf16(a_h[m], b_h[n], acc[m][n], 0,0,0);
                acc[m][n] = __builtin_amdgcn_mfma_f32_16x16x32_bf16(a_h[m], b_l[n], acc[m][n], 0,0,0);
                acc[m][n] = __builtin_amdgcn_mfma_f32_16x16x32_bf16(a_l[m], b_h[n], acc[m][n], 0,0,0);
            }
        if (ks + 1 < NKS) {
            __syncthreads();
            STAGE_WRITE((ks+1) & 1);
            __syncthreads();
            if (ks + 2 < NKS) STAGE_LOAD(ks+2);
        }
    }

    // ---- epilogue: tanh+bias into LDS Y[64][64], then float4 selector reduce
    int lr = l >> 4, lc = l & 15;
    __syncthreads();
    float* Y = (float*)Abuf;               // 16 KB
    #pragma unroll
    for (int n=0;n<2;++n) {
        int col_local = (wc*2 + n)*16 + lc;
        float bias = bias_c[cb*64 + col_local];
        #pragma unroll
        for (int m=0;m<2;++m) {
            int row_base = (wr*2 + m)*16 + lr*4;
            #pragma unroll
            for (int r=0;r<4;++r)
                Y[(row_base + r)*64 + col_local] = fast_tanh(acc[m][n][r] + bias);
        }
    }
    __syncthreads();
    #pragma unroll
    for (int it=0; it<2; ++it) {
        int task = tid + it*256;
        int q = task & 7, row = task >> 3;
        const float4* s8r = (const float4*)(S8 + q*NPAD + cb*64);
        const float4* yr  = (const float4*)(Y + row*64);
        float s = 0.f;
        #pragma unroll
        for (int c4=0;c4<16;++c4) {
            float4 a = yr[c4], b = s8r[c4];
            s += a.x*b.x + a.y*b.y + a.z*b.z + a.w*b.w;
        }
        partials[((size_t)cb*NRR + rb*64 + row)*8 + q] = s;
    }
    #undef STAGE_LOAD
    #undef STAGE_WRITE
}

// ---------------------------------------------------------------------------
// Kernel 4: rowvals[r][q] = sum over 32 col-blocks of partials
// ---------------------------------------------------------------------------
__global__ void finish_kernel(const float* __restrict__ partials,
                              float* __restrict__ rowvals) {
    int t = blockIdx.x*256 + threadIdx.x;   // 0..8191 = row*8 + q
    float s = 0.f;
    #pragma unroll 8
    for (int cbk = 0; cbk < 32; ++cbk) s += partials[(size_t)cbk*8192 + t];
    rowvals[t] = s;
}

// ---------------------------------------------------------------------------
// Kernel 5: fill both (B,N,N,N) outputs via exp factorization:
//  tanh(u) = 1 - 2/(e^{2u}+1);  e^{2(gi+gk+c+gj)} = Eik * Egj[j]
// ---------------------------------------------------------------------------
#define KSPLIT 2
__global__ __launch_bounds__(256) void fill_kernel(
        const float* __restrict__ rowvals, const float* __restrict__ consts,
        float* __restrict__ grand, float* __restrict__ sib) {
    int bi = blockIdx.x;          // b*128 + i
    int kz = blockIdx.y;
    int b = bi >> 7;
    int i = bi & 127;
    int tid = threadIdx.x;

    __shared__ float gks[128], sks[128], Egj[128], Esj[128];
    if (tid < 128) {
        const float* rv = rowvals + (size_t)(b*128 + tid)*8;
        gks[tid] = rv[2];
        sks[tid] = rv[5];
        Egj[tid] = __expf(2.f * rv[1]);
        Esj[tid] = __expf(2.f * rv[4]);
    }
    __syncthreads();

    const float* rvi = rowvals + (size_t)bi * 8;
    float c_g = consts[0], c_s = consts[1], c_r = consts[2];
    float gic = rvi[0] + c_g;
    float sic = rvi[3] + c_s;
    float r0 = rowvals[(size_t)(b*128)*8 + 7];
    float rootv = fast_tanh(r0 + rvi[6] + c_r);

    size_t base = (size_t)bi * (128*128);
    int j4 = (tid & 31) * 4;
    int klo = tid >> 5;                  // 0..7
    const int KROWS = 128 / KSPLIT;      // 64

    for (int it = 0; it < KROWS/8; ++it) {
        int k = kz*KROWS + it*8 + klo;
        float Eg = __expf(2.f * (gic + gks[k]));
        float Es = __expf(2.f * (sic + sks[k]));
        float4 go, so;
        #pragma unroll
        for (int jj = 0; jj < 4; ++jj) {
            int j = j4 + jj;
            bool valid = (i != 0) && (i != j) && (j != k);
            float tg = Eg * Egj[j];
            float ts = Es * Esj[j];
            float g = 1.f - 2.f * __builtin_amdgcn_rcpf(tg + 1.f);
            float s = 1.f - 2.f * __builtin_amdgcn_rcpf(ts + 1.f);
            g = valid ? g : NEG_HUGE;
            s = valid ? s : 0.0f;
            if (i != 0 && k == 0 && j == 0) g = rootv;
            (&go.x)[jj] = g;
            (&so.x)[jj] = s;
        }
        size_t off = base + (size_t)k*128 + j4;
        *(float4*)(grand + off) = go;
        *(float4*)(sib + off) = so;
    }
}

// ---------------------------------------------------------------------------
extern "C" void kernel_launch(void* const* d_in, const int* in_sizes, int n_in,
                              void* d_out, int out_size, void* d_ws, size_t ws_size,
                              hipStream_t stream) {
    const float* hidden = (const float*)d_in[0];
    const float* Wh  = (const float*)d_in[1];   const float* bh  = (const float*)d_in[2];
    const float* Wm  = (const float*)d_in[3];   const float* bm  = (const float*)d_in[4];
    const float* Ws_ = (const float*)d_in[5];   const float* bs  = (const float*)d_in[6];
    const float* Wg  = (const float*)d_in[7];   const float* bg  = (const float*)d_in[8];
    const float* W_gp = (const float*)d_in[9];  const float* b_gp = (const float*)d_in[10];
    const float* W_sp = (const float*)d_in[11]; const float* b_sp = (const float*)d_in[12];
    const float* W_rp = (const float*)d_in[13]; const float* b_rp = (const float*)d_in[14];
    const float* w_go = (const float*)d_in[15]; const float* b_go = (const float*)d_in[16];
    const float* w_so = (const float*)d_in[17]; const float* b_so = (const float*)d_in[18];

    float* out   = (float*)d_out;
    float* grand = out;                        // 16777216 floats
    float* sib   = out + (size_t)16777216;     // 16777216 floats

    // bf16 tiled scratch in the grand half of d_out (consumed by gemm,
    // overwritten by fill which runs last in stream order).
    uint4* A_t = (uint4*)out;                  // 16*25*512 uint4 (3.28 MB)
    uint4* B_t = (uint4*)out + 204800;         // 32*25*512 uint4 (6.55 MB)

    // small scratch in d_ws (~1.2 MB)
    float* S8      = (float*)d_ws;             // 8*2048
    float* bias_c  = S8 + 16384;               // 2048
    float* sel     = bias_c + 2048;            // 8*512 = 4096
    float* consts  = sel + 4096;               // 16
    float* rowvals = consts + 16;              // 8192
    float* partials= rowvals + 8192;           // 32*1024*8 = 262144

    prep_kernel<<<dim3(8), dim3(512), 0, stream>>>(W_gp, b_gp, W_sp, b_sp, W_rp, b_rp,
                                                   w_go, b_go, w_so, b_so, sel, consts);
    prep2_kernel<<<dim3(8), dim3(256), 0, stream>>>(sel, bh, bm, bs, bg, S8, bias_c);
    convert_kernel<<<dim3(240), dim3(256), 0, stream>>>(hidden, Wh, Wm, Ws_, Wg, A_t, B_t);
    gemm_kernel<<<dim3(32,16), dim3(256), 0, stream>>>(A_t, B_t, S8, bias_c, partials);
    finish_kernel<<<dim3(32), dim3(256), 0, stream>>>(partials, rowvals);
    fill_kernel<<<dim3(1024, KSPLIT), dim3(256), 0, stream>>>(rowvals, consts, grand, sib);
}

// Round 6
// 112.684 us; speedup vs baseline: 2.1154x; 1.0683x over previous
//
#include <hip/hip_runtime.h>
#include <math.h>

// B=8, N=128, H2=800, FD=500, P=100
#define FD 500
#define H2 800
#define NRR 1024          // rows = 8*128
#define NPAD 2048         // padded feature cols (2000 real)
#define NKS 25            // 800 / 32

#define NEG_HUGE (-1.0e30f)  // stands in for -inf (ref has -inf -> threshold inf)

typedef __bf16 bf16x8 __attribute__((ext_vector_type(8)));
typedef float f32x4 __attribute__((ext_vector_type(4)));

union ChunkU { uint4 u; bf16x8 b; __bf16 h[8]; };

__device__ __forceinline__ float fast_tanh(float x) {
    float e = __expf(2.0f * x);
    return 1.0f - 2.0f / (e + 1.0f);
}

__device__ __forceinline__ bf16x8 as_frag(uint4 v) { ChunkU c; c.u = v; return c.b; }

// ---------------------------------------------------------------------------
// Kernel 1: prep — S8[8][2048], bias_c[2048], consts[3], all computed directly
//  (each thread does its own 1-3 selector dot products; no sel intermediate).
//  S8 q-map: 0=gi(mod) 1=gj(head) 2=gk(grd) 3=si(mod) 4=sj(sib) 5=sk(head)
//            6=ri(mod) 7=r0h(head)
// ---------------------------------------------------------------------------
__global__ __launch_bounds__(256) void prep_kernel(
        const float* __restrict__ W_gp, const float* __restrict__ b_gp,
        const float* __restrict__ W_sp, const float* __restrict__ b_sp,
        const float* __restrict__ W_rp, const float* __restrict__ b_rp,
        const float* __restrict__ w_go, const float* __restrict__ b_go,
        const float* __restrict__ w_so, const float* __restrict__ b_so,
        const float* __restrict__ bh, const float* __restrict__ bm,
        const float* __restrict__ bs, const float* __restrict__ bg,
        float* __restrict__ S8, float* __restrict__ bias_c,
        float* __restrict__ consts) {
    int c = blockIdx.x * 256 + threadIdx.x;   // 0..2047
    float v[8] = {0,0,0,0,0,0,0,0};
    float bias = 0.f;
    if (c < 2000) {
        int t = c / FD, f = c % FD;
        float s0 = 0.f, s1 = 0.f, s2 = 0.f;
        if (t == 0) {          // head: gj = w_go.Wgp[:,Fd+f]; sk = w_so.Wsp[:,f]; r0h = w_go.Wrp[:,f]
            #pragma unroll 4
            for (int p = 0; p < 100; ++p) {
                s0 += w_go[p] * W_gp[p*1500 + 500 + f];
                s1 += w_so[p] * W_sp[p*1500 + f];
                s2 += w_go[p] * W_rp[p*1000 + f];
            }
            v[1] = s0; v[5] = s1; v[7] = s2; bias = bh[f];
        } else if (t == 1) {   // mod: gi = w_go.Wgp[:,2Fd+f]; si = w_so.Wsp[:,2Fd+f]; ri = w_go.Wrp[:,Fd+f]
            #pragma unroll 4
            for (int p = 0; p < 100; ++p) {
                s0 += w_go[p] * W_gp[p*1500 + 1000 + f];
                s1 += w_so[p] * W_sp[p*1500 + 1000 + f];
                s2 += w_go[p] * W_rp[p*1000 + 500 + f];
            }
            v[0] = s0; v[3] = s1; v[6] = s2; bias = bm[f];
        } else if (t == 2) {   // sib: sj = w_so.Wsp[:,Fd+f]
            #pragma unroll 4
            for (int p = 0; p < 100; ++p) s0 += w_so[p] * W_sp[p*1500 + 500 + f];
            v[4] = s0; bias = bs[f];
        } else {               // grd: gk = w_go.Wgp[:,f]
            #pragma unroll 4
            for (int p = 0; p < 100; ++p) s0 += w_go[p] * W_gp[p*1500 + f];
            v[2] = s0; bias = bg[f];
        }
    }
    #pragma unroll
    for (int q = 0; q < 8; ++q) S8[q*NPAD + c] = v[q];
    bias_c[c] = bias;
    if (c < 3) {
        const float* bv = (c==0) ? b_gp : (c==1) ? b_sp : b_rp;
        const float* wv = (c==1) ? w_so : w_go;
        float s = (c==1) ? b_so[0] : b_go[0];
        for (int p = 0; p < 100; ++p) s += bv[p] * wv[p];
        consts[c] = s;
    }
}

// ---------------------------------------------------------------------------
// Kernel 2: MFMA GEMM with FUSED f32->bf16 hi/lo conversion in reg-staging
//  (no pre-tiled A_t/B_t round trip). Block tile 64x64, 4 waves, KS=32,
//  double-buffered LDS, fragment-linear chunks. Epilogue: tanh+bias ->
//  LDS Y -> selector reduce -> partials.
//  Staging map: threads 0-127 stage A, 128-255 stage B. Thread handles
//  fragment rows fgrp and fgrp+2 (fgrp = (tid&127)>>6), lane sl=tid&63:
//  row = frag*16 + (sl&15), k = ks*32 + (sl>>4)*8 .. +7 (8 floats, 2xfloat4;
//  lanes {sl, sl^16, sl^32, sl^48} cover 128 contiguous bytes of one row).
// ---------------------------------------------------------------------------
__global__ __launch_bounds__(256, 2) void gemm_kernel(
        const float* __restrict__ hidden,
        const float* __restrict__ Wh, const float* __restrict__ Wm,
        const float* __restrict__ Ws, const float* __restrict__ Wg,
        const float* __restrict__ S8, const float* __restrict__ bias_c,
        float* __restrict__ partials) {
    __shared__ uint4 Abuf[2][512];
    __shared__ uint4 Bbuf[2][512];
    int tid = threadIdx.x;
    int cb = blockIdx.x;    // 0..31
    int rb = blockIdx.y;    // 0..15

    int l  = tid & 63;
    int wid = tid >> 6;
    int wr = wid >> 1, wc = wid & 1;

    // ---- staging source setup (uniform per wave) ----
    bool stA = tid < 128;
    int ts = tid & 127;
    int fgrp = ts >> 6;                 // 0 or 1
    int sl = ts & 63;
    int r0 = fgrp*16 + (sl & 15);       // fragment fgrp
    int r1 = (fgrp+2)*16 + (sl & 15);   // fragment fgrp+2
    int koff = (sl >> 4) * 8;
    const float* src0 = nullptr;
    const float* src1 = nullptr;
    if (stA) {
        src0 = hidden + (size_t)(rb*64 + r0) * H2 + koff;
        src1 = hidden + (size_t)(rb*64 + r1) * H2 + koff;
    } else {
        int c0 = cb*64 + r0, c1 = cb*64 + r1;
        if (c0 < 2000) {
            int wt = c0 / FD, wf = c0 % FD;
            const float* wm = (wt==0)?Wh:(wt==1)?Wm:(wt==2)?Ws:Wg;
            src0 = wm + (size_t)wf * H2 + koff;
        }
        if (c1 < 2000) {
            int wt = c1 / FD, wf = c1 % FD;
            const float* wm = (wt==0)?Wh:(wt==1)?Wm:(wt==2)?Ws:Wg;
            src1 = wm + (size_t)wf * H2 + koff;
        }
    }
    uint4* mybuf0 = stA ? &Abuf[0][0] : &Bbuf[0][0];
    uint4* mybuf1 = stA ? &Abuf[1][0] : &Bbuf[1][0];

    float4 ld[4];   // two rows x 8 floats
    #define STAGE_LOAD(ks) do { \
        const float4 z_ = {0.f,0.f,0.f,0.f}; \
        ld[0] = src0 ? *(const float4*)(src0 + (ks)*32)     : z_; \
        ld[1] = src0 ? *(const float4*)(src0 + (ks)*32 + 4) : z_; \
        ld[2] = src1 ? *(const float4*)(src1 + (ks)*32)     : z_; \
        ld[3] = src1 ? *(const float4*)(src1 + (ks)*32 + 4) : z_; } while(0)

    // convert 8 floats -> hi/lo chunks and write to LDS (fragment-linear)
    #define CONV_WRITE(bufsel) do { \
        uint4* d_ = (bufsel) ? mybuf1 : mybuf0; \
        ChunkU h0_, l0_, h1_, l1_; \
        const float* xf = (const float*)ld; \
        _Pragma("unroll") \
        for (int j = 0; j < 8; ++j) { \
            float x0 = xf[j], x1 = xf[8+j]; \
            __bf16 h0 = (__bf16)x0; h0_.h[j] = h0; l0_.h[j] = (__bf16)(x0 - (float)h0); \
            __bf16 h1 = (__bf16)x1; h1_.h[j] = h1; l1_.h[j] = (__bf16)(x1 - (float)h1); \
        } \
        d_[(fgrp    )*64 + sl] = h0_.u; \
        d_[(fgrp + 2)*64 + sl] = h1_.u; \
        d_[(4 + fgrp)*64 + sl] = l0_.u; \
        d_[(6 + fgrp)*64 + sl] = l1_.u; } while(0)

    f32x4 acc[2][2];
    #pragma unroll
    for (int m=0;m<2;++m)
        #pragma unroll
        for (int n=0;n<2;++n) acc[m][n] = (f32x4){0.f,0.f,0.f,0.f};

    STAGE_LOAD(0); CONV_WRITE(0);
    __syncthreads();
    STAGE_LOAD(1);

    for (int ks = 0; ks < NKS; ++ks) {
        int cur = ks & 1;
        int fa = wr*2, fb = wc*2;
        bf16x8 a_h[2], a_l[2], b_h[2], b_l[2];
        #pragma unroll
        for (int m=0;m<2;++m) {
            a_h[m] = as_frag(Abuf[cur][(0 + fa + m)*64 + l]);
            a_l[m] = as_frag(Abuf[cur][(4 + fa + m)*64 + l]);
        }
        #pragma unroll
        for (int n=0;n<2;++n) {
            b_h[n] = as_frag(Bbuf[cur][(0 + fb + n)*64 + l]);
            b_l[n] = as_frag(Bbuf[cur][(4 + fb + n)*64 + l]);
        }
        #pragma unroll
        for (int m=0;m<2;++m)
            #pragma unroll
            for (int n=0;n<2;++n) {
                acc[m][n] = __builtin_amdgcn_mfma_f32_16x16x32_bf16(a_h[m], b_h[n], acc[m][n], 0,0,0);
                acc[m][n] = __builtin_amdgcn_mfma_f32_16x16x32_bf16(a_h[m], b_l[n], acc[m][n], 0,0,0);
                acc[m][n] = __builtin_amdgcn_mfma_f32_16x16x32_bf16(a_l[m], b_h[n], acc[m][n], 0,0,0);
            }
        if (ks + 1 < NKS) {
            __syncthreads();
            CONV_WRITE((ks+1) & 1);
            __syncthreads();
            if (ks + 2 < NKS) STAGE_LOAD(ks+2);
        }
    }

    // ---- epilogue: tanh+bias into LDS Y[64][64], then float4 selector reduce
    int lr = l >> 4, lc = l & 15;
    __syncthreads();
    float* Y = (float*)Abuf;               // 16 KB
    #pragma unroll
    for (int n=0;n<2;++n) {
        int col_local = (wc*2 + n)*16 + lc;
        float bias = bias_c[cb*64 + col_local];
        #pragma unroll
        for (int m=0;m<2;++m) {
            int row_base = (wr*2 + m)*16 + lr*4;
            #pragma unroll
            for (int r=0;r<4;++r)
                Y[(row_base + r)*64 + col_local] = fast_tanh(acc[m][n][r] + bias);
        }
    }
    __syncthreads();
    #pragma unroll
    for (int it=0; it<2; ++it) {
        int task = tid + it*256;
        int q = task & 7, row = task >> 3;
        const float4* s8r = (const float4*)(S8 + q*NPAD + cb*64);
        const float4* yr  = (const float4*)(Y + row*64);
        float s = 0.f;
        #pragma unroll
        for (int c4=0;c4<16;++c4) {
            float4 a = yr[c4], b = s8r[c4];
            s += a.x*b.x + a.y*b.y + a.z*b.z + a.w*b.w;
        }
        partials[((size_t)cb*NRR + rb*64 + row)*8 + q] = s;
    }
    #undef STAGE_LOAD
    #undef CONV_WRITE
}

// ---------------------------------------------------------------------------
// Kernel 3: rowvals[r][q] = sum over 32 col-blocks of partials
// ---------------------------------------------------------------------------
__global__ void finish_kernel(const float* __restrict__ partials,
                              float* __restrict__ rowvals) {
    int t = blockIdx.x*256 + threadIdx.x;   // 0..8191 = row*8 + q
    float s = 0.f;
    #pragma unroll 8
    for (int cbk = 0; cbk < 32; ++cbk) s += partials[(size_t)cbk*8192 + t];
    rowvals[t] = s;
}

// ---------------------------------------------------------------------------
// Kernel 4: fill both (B,N,N,N) outputs via exp factorization:
//  tanh(u) = 1 - 2/(e^{2u}+1);  e^{2(gi+gk+c+gj)} = Eik * Egj[j]
// ---------------------------------------------------------------------------
#define KSPLIT 2
__global__ __launch_bounds__(256) void fill_kernel(
        const float* __restrict__ rowvals, const float* __restrict__ consts,
        float* __restrict__ grand, float* __restrict__ sib) {
    int bi = blockIdx.x;          // b*128 + i
    int kz = blockIdx.y;
    int b = bi >> 7;
    int i = bi & 127;
    int tid = threadIdx.x;

    __shared__ float gks[128], sks[128], Egj[128], Esj[128];
    if (tid < 128) {
        const float* rv = rowvals + (size_t)(b*128 + tid)*8;
        gks[tid] = rv[2];
        sks[tid] = rv[5];
        Egj[tid] = __expf(2.f * rv[1]);
        Esj[tid] = __expf(2.f * rv[4]);
    }
    __syncthreads();

    const float* rvi = rowvals + (size_t)bi * 8;
    float c_g = consts[0], c_s = consts[1], c_r = consts[2];
    float gic = rvi[0] + c_g;
    float sic = rvi[3] + c_s;
    float r0 = rowvals[(size_t)(b*128)*8 + 7];
    float rootv = fast_tanh(r0 + rvi[6] + c_r);

    size_t base = (size_t)bi * (128*128);
    int j4 = (tid & 31) * 4;
    int klo = tid >> 5;                  // 0..7
    const int KROWS = 128 / KSPLIT;      // 64

    for (int it = 0; it < KROWS/8; ++it) {
        int k = kz*KROWS + it*8 + klo;
        float Eg = __expf(2.f * (gic + gks[k]));
        float Es = __expf(2.f * (sic + sks[k]));
        float4 go, so;
        #pragma unroll
        for (int jj = 0; jj < 4; ++jj) {
            int j = j4 + jj;
            bool valid = (i != 0) && (i != j) && (j != k);
            float tg = Eg * Egj[j];
            float ts = Es * Esj[j];
            float g = 1.f - 2.f * __builtin_amdgcn_rcpf(tg + 1.f);
            float s = 1.f - 2.f * __builtin_amdgcn_rcpf(ts + 1.f);
            g = valid ? g : NEG_HUGE;
            s = valid ? s : 0.0f;
            if (i != 0 && k == 0 && j == 0) g = rootv;
            (&go.x)[jj] = g;
            (&so.x)[jj] = s;
        }
        size_t off = base + (size_t)k*128 + j4;
        *(float4*)(grand + off) = go;
        *(float4*)(sib + off) = so;
    }
}

// ---------------------------------------------------------------------------
extern "C" void kernel_launch(void* const* d_in, const int* in_sizes, int n_in,
                              void* d_out, int out_size, void* d_ws, size_t ws_size,
                              hipStream_t stream) {
    const float* hidden = (const float*)d_in[0];
    const float* Wh  = (const float*)d_in[1];   const float* bh  = (const float*)d_in[2];
    const float* Wm  = (const float*)d_in[3];   const float* bm  = (const float*)d_in[4];
    const float* Ws_ = (const float*)d_in[5];   const float* bs  = (const float*)d_in[6];
    const float* Wg  = (const float*)d_in[7];   const float* bg  = (const float*)d_in[8];
    const float* W_gp = (const float*)d_in[9];  const float* b_gp = (const float*)d_in[10];
    const float* W_sp = (const float*)d_in[11]; const float* b_sp = (const float*)d_in[12];
    const float* W_rp = (const float*)d_in[13]; const float* b_rp = (const float*)d_in[14];
    const float* w_go = (const float*)d_in[15]; const float* b_go = (const float*)d_in[16];
    const float* w_so = (const float*)d_in[17]; const float* b_so = (const float*)d_in[18];

    float* out   = (float*)d_out;
    float* grand = out;                        // 16777216 floats
    float* sib   = out + (size_t)16777216;     // 16777216 floats

    // all scratch in d_ws (~1.2 MB)
    float* S8      = (float*)d_ws;             // 8*2048 = 16384
    float* bias_c  = S8 + 16384;               // 2048
    float* consts  = bias_c + 2048;            // 16
    float* rowvals = consts + 16;              // 8192
    float* partials= rowvals + 8192;           // 32*1024*8 = 262144

    prep_kernel<<<dim3(8), dim3(256), 0, stream>>>(
        W_gp, b_gp, W_sp, b_sp, W_rp, b_rp, w_go, b_go, w_so, b_so,
        bh, bm, bs, bg, S8, bias_c, consts);
    gemm_kernel<<<dim3(32,16), dim3(256), 0, stream>>>(
        hidden, Wh, Wm, Ws_, Wg, S8, bias_c, partials);
    finish_kernel<<<dim3(32), dim3(256), 0, stream>>>(partials, rowvals);
    fill_kernel<<<dim3(1024, KSPLIT), dim3(256), 0, stream>>>(rowvals, consts, grand, sib);
}